// Round 10
// baseline (1948.451 us; speedup 1.0000x reference)
//
#include <hip/hip_runtime.h>

#define DIN 256
#define DH  128
#define DOUT 64
#define BSH  7          // bucket = 128 nodes
#define BNODES 128
#define MAXBUK 400      // >= ceil(N/128); N=50000 -> 391
#define NBLK 512        // histogram/scatter grid
#define NRANGE 4        // src ranges (phases)
#define RSH  14         // src range = src >> 14
#define KOWN 8          // nodes owned per wave (dynamic slot in LDS acc)

typedef unsigned int  u32;
typedef unsigned short u16;
typedef __attribute__((ext_vector_type(8))) short bf16x8;
typedef __attribute__((ext_vector_type(4))) float f32x4;

__device__ inline u16 f2bf(float f) {            // fp32 -> bf16 round-nearest-even
  u32 u = __float_as_uint(f);
  u32 r = u + 0x7FFF + ((u >> 16) & 1);
  return (u16)(r >> 16);
}
__device__ inline float bf2f_lo(u32 packed) { return __uint_as_float(packed << 16); }
__device__ inline float bf2f_hi(u32 packed) { return __uint_as_float(packed & 0xFFFF0000u); }

// ---------- radix-style CSR construction (no global atomics) ----------

__global__ __launch_bounds__(256) void hist_kernel(const int* __restrict__ dst,
    int* __restrict__ counts, int E, int nbuk) {
  __shared__ int h[MAXBUK];
  int tid = threadIdx.x, b = blockIdx.x;
  for (int i = tid; i < nbuk; i += 256) h[i] = 0;
  __syncthreads();
  int ech = (E + NBLK - 1) / NBLK;
  int e0 = b * ech, e1 = min(E, e0 + ech);
  for (int e = e0 + tid; e < e1; e += 256)
    atomicAdd(&h[dst[e] >> BSH], 1);
  __syncthreads();
  for (int i = tid; i < nbuk; i += 256) counts[(size_t)i * NBLK + b] = h[i];
}

__global__ __launch_bounds__(256) void col_scan(int* __restrict__ counts,
    int* __restrict__ colsum, int nbuk) {
  __shared__ int sm[256];
  __shared__ int carry;
  int buk = blockIdx.x, t = threadIdx.x;
  if (t == 0) carry = 0;
  __syncthreads();
  int* row = counts + (size_t)buk * NBLK;
  for (int base = 0; base < NBLK; base += 256) {
    int v = row[base + t];
    sm[t] = v;
    __syncthreads();
    for (int d = 1; d < 256; d <<= 1) {
      int a = (t >= d) ? sm[t - d] : 0;
      __syncthreads();
      sm[t] += a;
      __syncthreads();
    }
    int excl = sm[t] - v + carry;
    row[base + t] = excl;
    __syncthreads();
    if (t == 255) carry = excl + v;
    __syncthreads();
  }
  if (t == 0) colsum[buk] = carry;
}

__global__ __launch_bounds__(256) void scan_block(int* partial, int* total_out, int nb, int n) {
  __shared__ int sm[256];
  __shared__ int carry;
  int t = threadIdx.x;
  if (t == 0) carry = 0;
  __syncthreads();
  for (int base = 0; base < nb; base += 256) {
    int g = base + t;
    int v = (g < nb) ? partial[g] : 0;
    sm[t] = v;
    __syncthreads();
    for (int d = 1; d < 256; d <<= 1) {
      int add = (t >= d) ? sm[t - d] : 0;
      __syncthreads();
      sm[t] += add;
      __syncthreads();
    }
    int excl = sm[t] - v + carry;
    if (g < nb) partial[g] = excl;
    __syncthreads();
    if (t == 255) carry = excl + v;
    __syncthreads();
  }
  if (t == 0) total_out[n] = carry;
}

__global__ __launch_bounds__(256) void scatter_kernel(const int* __restrict__ src,
    const int* __restrict__ dst, const int* __restrict__ counts,
    const int* __restrict__ bb, u32* __restrict__ ebuf, int E, int nbuk) {
  __shared__ int cur[MAXBUK];
  int tid = threadIdx.x, b = blockIdx.x;
  for (int i = tid; i < nbuk; i += 256)
    cur[i] = bb[i] + counts[(size_t)i * NBLK + b];
  __syncthreads();
  int ech = (E + NBLK - 1) / NBLK;
  int e0 = b * ech, e1 = min(E, e0 + ech);
  for (int e = e0 + tid; e < e1; e += 256) {
    int d = dst[e];
    int r = atomicAdd(&cur[d >> BSH], 1);
    ebuf[r] = (u32)src[e] | ((u32)(d & (BNODES - 1)) << 16);   // N < 65536
  }
}

// per-bucket: per-node degree (-> dinv) and per-(wave,phase) counts.
// wave = node/KOWN; bucket has BNODES/KOWN = 16 waves -> 64 (wave,phase) cells.
__global__ __launch_bounds__(256) void bucket_node_count(const u32* __restrict__ ebuf,
    const int* __restrict__ bb, int* __restrict__ cnt, float* __restrict__ dinv, int N) {
  __shared__ int cn[BNODES];
  __shared__ int cwp[64];
  int b = blockIdx.x, tid = threadIdx.x;
  if (tid < BNODES) cn[tid] = 0;
  if (tid < 64) cwp[tid] = 0;
  __syncthreads();
  int e0 = bb[b], e1 = bb[b + 1];
  for (int e = e0 + tid; e < e1; e += 256) {
    u32 p = ebuf[e];
    int nl = p >> 16;
    u32 s = p & 0xFFFFu;
    atomicAdd(&cn[nl], 1);
    atomicAdd(&cwp[(nl >> 3) * NRANGE + (int)(s >> RSH)], 1);
  }
  __syncthreads();
  if (tid < 64) cnt[b * 64 + tid] = cwp[tid];
  int node = b * BNODES + tid;
  if (tid < BNODES && node < N) dinv[node] = rsqrtf((float)(cn[tid] + 1));
}

__global__ __launch_bounds__(256) void reduce_chunks(const int* __restrict__ cnt,
                                                     int* __restrict__ partial, int n) {
  int t = threadIdx.x;
  int g = blockIdx.x * 256 + t;
  int v = (g < n) ? cnt[g] : 0;
  #pragma unroll
  for (int o = 32; o > 0; o >>= 1) v += __shfl_down(v, o, 64);
  __shared__ int sm[4];
  if ((t & 63) == 0) sm[t >> 6] = v;
  __syncthreads();
  if (t == 0) partial[blockIdx.x] = sm[0] + sm[1] + sm[2] + sm[3];
}

__global__ __launch_bounds__(256) void scan_chunks(const int* __restrict__ cnt,
    const int* __restrict__ chunkoff, int* __restrict__ rowptr, int n) {
  __shared__ int sm[256];
  int t = threadIdx.x, g = blockIdx.x * 256 + t;
  int v = (g < n) ? cnt[g] : 0;
  sm[t] = v;
  __syncthreads();
  for (int d = 1; d < 256; d <<= 1) {
    int add = (t >= d) ? sm[t - d] : 0;
    __syncthreads();
    sm[t] += add;
    __syncthreads();
  }
  if (g < n) rowptr[g] = sm[t] - v + chunkoff[blockIdx.x];
}

// fill csr32 entries (k<<16 | src) into per-(wave,phase) segments
__global__ __launch_bounds__(256) void bucket_fill(const u32* __restrict__ ebuf,
    const int* __restrict__ bb, const int* __restrict__ rowptr,
    u32* __restrict__ csr32) {
  __shared__ int cur[64];
  int b = blockIdx.x, tid = threadIdx.x;
  if (tid < 64) cur[tid] = rowptr[b * 64 + tid];
  __syncthreads();
  int e0 = bb[b], e1 = bb[b + 1];
  for (int e = e0 + tid; e < e1; e += 256) {
    u32 p = ebuf[e];
    int nl = p >> 16;
    u32 s = p & 0xFFFFu;
    int pos = atomicAdd(&cur[(nl >> 3) * NRANGE + (int)(s >> RSH)], 1);
    csr32[pos] = ((u32)(nl & (KOWN - 1)) << 16) | s;
  }
}

// ---------- W1,W2 -> bf16 transposed (one-shot, tiny) ----------

__global__ __launch_bounds__(256) void w_prep(const float* __restrict__ W1,
    const float* __restrict__ W2, u16* __restrict__ w1t, u16* __restrict__ w2t) {
  int t = blockIdx.x * 256 + threadIdx.x;     // 40960 threads
  if (t < DH * DIN) {
    int n = t >> 8, k = t & 255;
    w1t[t] = f2bf(W1[k * DH + n]);            // w1t[n*256+k]
  } else {
    int t2 = t - DH * DIN;
    int n = t2 >> 7, k = t2 & 127;
    w2t[t2] = f2bf(W2[k * DOUT + n]);         // w2t[n*128+k]
  }
}

// ---------- GEMM1: bf16 MFMA, BM=64 BN=128 BK=64, epilogue dinv*bf16 ----------

__global__ __launch_bounds__(256) void gemm1_mfma(const float* __restrict__ x,
    const u16* __restrict__ w1t, const float* __restrict__ dinv,
    u16* __restrict__ h1, int M) {
  __shared__ u16 As[64][72];
  __shared__ u16 Bs[128][72];
  const int tid = threadIdx.x;
  const int lane = tid & 63, w = tid >> 6;
  const int row16 = lane & 15, quad = lane >> 4;
  const int rowBase = blockIdx.x * 64;
  f32x4 acc[8];
  #pragma unroll
  for (int nt = 0; nt < 8; ++nt) acc[nt] = (f32x4)(0.f);

  for (int kt = 0; kt < DIN; kt += 64) {
    {
      int r = tid >> 2, kq = tid & 3;
      int grow = rowBase + r;
      #pragma unroll
      for (int i = 0; i < 4; ++i) {
        float4 v = make_float4(0.f, 0.f, 0.f, 0.f);
        if (grow < M) v = *(const float4*)&x[(size_t)grow * DIN + kt + kq * 16 + i * 4];
        u32 lo = (u32)f2bf(v.x) | ((u32)f2bf(v.y) << 16);
        u32 hi = (u32)f2bf(v.z) | ((u32)f2bf(v.w) << 16);
        *(uint2*)&As[r][kq * 16 + i * 4] = make_uint2(lo, hi);
      }
    }
    {
      int n = tid >> 1, half = tid & 1;
      const uint4* s = (const uint4*)&w1t[n * DIN + kt + half * 32];
      uint4* d = (uint4*)&Bs[n][half * 32];
      d[0] = s[0]; d[1] = s[1]; d[2] = s[2]; d[3] = s[3];
    }
    __syncthreads();
    #pragma unroll
    for (int ks = 0; ks < 64; ks += 32) {
      bf16x8 a = *(bf16x8*)&As[w * 16 + row16][ks + quad * 8];
      #pragma unroll
      for (int nt = 0; nt < 8; ++nt) {
        bf16x8 b = *(bf16x8*)&Bs[nt * 16 + row16][ks + quad * 8];
        acc[nt] = __builtin_amdgcn_mfma_f32_16x16x32_bf16(a, b, acc[nt], 0, 0, 0);
      }
    }
    __syncthreads();
  }
  #pragma unroll
  for (int reg = 0; reg < 4; ++reg) {
    int row = rowBase + w * 16 + quad * 4 + reg;
    if (row < M) {
      float s = dinv[row];
      #pragma unroll
      for (int nt = 0; nt < 8; ++nt)
        h1[(size_t)row * DH + nt * 16 + row16] = f2bf(acc[nt][reg] * s);
    }
  }
}

// ---------- GEMM2: bf16 MFMA, BM=64 BN=64, K=128 staged once ----------

__global__ __launch_bounds__(256) void gemm2_mfma(const u16* __restrict__ g1,
    const u16* __restrict__ w2t, const float* __restrict__ dinv,
    u16* __restrict__ h2, int M) {
  __shared__ u16 As[64][136];
  __shared__ u16 Bs[64][136];
  const int tid = threadIdx.x;
  const int lane = tid & 63, w = tid >> 6;
  const int row16 = lane & 15, quad = lane >> 4;
  const int rowBase = blockIdx.x * 64;
  f32x4 acc[4];
  #pragma unroll
  for (int nt = 0; nt < 4; ++nt) acc[nt] = (f32x4)(0.f);

  #pragma unroll
  for (int i = 0; i < 4; ++i) {
    int flat = i * 256 + tid;
    int r = flat >> 4, c = flat & 15;
    int grow = rowBase + r;
    uint4 v = make_uint4(0, 0, 0, 0);
    if (grow < M) v = *(const uint4*)&g1[(size_t)grow * DH + c * 8];
    *(uint4*)&As[r][c * 8] = v;
  }
  #pragma unroll
  for (int i = 0; i < 4; ++i) {
    int flat = i * 256 + tid;
    int r = flat >> 4, c = flat & 15;
    *(uint4*)&Bs[r][c * 8] = *(const uint4*)&w2t[r * DH + c * 8];
  }
  __syncthreads();
  #pragma unroll
  for (int ks = 0; ks < 128; ks += 32) {
    bf16x8 a = *(bf16x8*)&As[w * 16 + row16][ks + quad * 8];
    #pragma unroll
    for (int nt = 0; nt < 4; ++nt) {
      bf16x8 b = *(bf16x8*)&Bs[nt * 16 + row16][ks + quad * 8];
      acc[nt] = __builtin_amdgcn_mfma_f32_16x16x32_bf16(a, b, acc[nt], 0, 0, 0);
    }
  }
  #pragma unroll
  for (int reg = 0; reg < 4; ++reg) {
    int row = rowBase + w * 16 + quad * 4 + reg;
    if (row < M) {
      float s = dinv[row];
      #pragma unroll
      for (int nt = 0; nt < 4; ++nt)
        h2[(size_t)row * DOUT + nt * 16 + row16] = f2bf(acc[nt][reg] * s);
    }
  }
}

// ---------- phased pull aggregation: wave owns KOWN nodes, LDS accumulators ----------
// Flat per-(wave,phase) edge list, owner slot k packed in entry (k<<16|src).
// 16-deep gather batches; ds_add_f32 (fire-and-forget) into wave-private LDS.
// No barriers: acc regions are wave-exclusive. Phase r touches only a ~4 MB
// slice of h -> L2-friendly (soft phasing, verified byte reduction in R9).

__global__ __launch_bounds__(256, 6) void aggregate1w(const u16* __restrict__ h,
    const int* __restrict__ rowptr, const u32* __restrict__ csr32,
    const float* __restrict__ dinv, const float* __restrict__ bias,
    u16* __restrict__ out, int n, int nwave) {
  __shared__ float2 accs[4][KOWN][64];   // 16 KB
  const u32* h32 = (const u32*)h;
  int lane = threadIdx.x & 63;
  int wid = threadIdx.x >> 6;
  int gw = __builtin_amdgcn_readfirstlane(blockIdx.x * 4 + wid);
  if (gw >= nwave) return;
  #pragma unroll
  for (int k = 0; k < KOWN; ++k) {       // init with self-loop term (pre-scaled h)
    int nd = gw * KOWN + k;
    float2 v = make_float2(0.f, 0.f);
    if (nd < n) {
      u32 w0 = h32[(size_t)nd * (DH / 2) + lane];
      v.x = bf2f_lo(w0); v.y = bf2f_hi(w0);
    }
    accs[wid][k][lane] = v;
  }
  int segbase = gw * NRANGE;
  for (int r = 0; r < NRANGE; ++r) {
    int p = rowptr[segbase + r], pe = rowptr[segbase + r + 1];
    for (; p + 16 <= pe; p += 16) {
      u32 e[16], w[16];
      #pragma unroll
      for (int j = 0; j < 16; ++j) e[j] = csr32[p + j];
      #pragma unroll
      for (int j = 0; j < 16; ++j)
        w[j] = h32[(size_t)(e[j] & 0xFFFFu) * (DH / 2) + lane];
      #pragma unroll
      for (int j = 0; j < 16; ++j) {
        int k = (int)(e[j] >> 16);
        atomicAdd(&accs[wid][k][lane].x, bf2f_lo(w[j]));
        atomicAdd(&accs[wid][k][lane].y, bf2f_hi(w[j]));
      }
    }
    for (; p + 4 <= pe; p += 4) {
      u32 e[4], w[4];
      #pragma unroll
      for (int j = 0; j < 4; ++j) e[j] = csr32[p + j];
      #pragma unroll
      for (int j = 0; j < 4; ++j)
        w[j] = h32[(size_t)(e[j] & 0xFFFFu) * (DH / 2) + lane];
      #pragma unroll
      for (int j = 0; j < 4; ++j) {
        int k = (int)(e[j] >> 16);
        atomicAdd(&accs[wid][k][lane].x, bf2f_lo(w[j]));
        atomicAdd(&accs[wid][k][lane].y, bf2f_hi(w[j]));
      }
    }
    for (; p < pe; ++p) {
      u32 e = csr32[p];
      u32 w = h32[(size_t)(e & 0xFFFFu) * (DH / 2) + lane];
      int k = (int)(e >> 16);
      atomicAdd(&accs[wid][k][lane].x, bf2f_lo(w));
      atomicAdd(&accs[wid][k][lane].y, bf2f_hi(w));
    }
  }
  int c0 = lane * 2;
  #pragma unroll
  for (int k = 0; k < KOWN; ++k) {
    int nd = gw * KOWN + k;
    if (nd < n) {
      float di = dinv[nd];
      float2 a = accs[wid][k][lane];
      float fx = fmaxf(fmaf(a.x, di, bias[c0]), 0.f);
      float fy = fmaxf(fmaf(a.y, di, bias[c0 + 1]), 0.f);
      *(u32*)&out[(size_t)nd * DH + c0] = (u32)f2bf(fx) | ((u32)f2bf(fy) << 16);
    }
  }
}

__global__ __launch_bounds__(256, 6) void aggregate2w(const u16* __restrict__ h,
    const int* __restrict__ rowptr, const u32* __restrict__ csr32,
    const float* __restrict__ dinv, const float* __restrict__ bias,
    float* __restrict__ out, int n, int nwave) {
  __shared__ float accs[4][KOWN][64];    // 8 KB
  int lane = threadIdx.x & 63;
  int wid = threadIdx.x >> 6;
  int gw = __builtin_amdgcn_readfirstlane(blockIdx.x * 4 + wid);
  if (gw >= nwave) return;
  #pragma unroll
  for (int k = 0; k < KOWN; ++k) {
    int nd = gw * KOWN + k;
    float v = 0.f;
    if (nd < n) v = __uint_as_float((u32)h[(size_t)nd * DOUT + lane] << 16);
    accs[wid][k][lane] = v;
  }
  int segbase = gw * NRANGE;
  for (int r = 0; r < NRANGE; ++r) {
    int p = rowptr[segbase + r], pe = rowptr[segbase + r + 1];
    for (; p + 16 <= pe; p += 16) {
      u32 e[16], w[16];
      #pragma unroll
      for (int j = 0; j < 16; ++j) e[j] = csr32[p + j];
      #pragma unroll
      for (int j = 0; j < 16; ++j)
        w[j] = (u32)h[(size_t)(e[j] & 0xFFFFu) * DOUT + lane];
      #pragma unroll
      for (int j = 0; j < 16; ++j)
        atomicAdd(&accs[wid][(int)(e[j] >> 16)][lane], __uint_as_float(w[j] << 16));
    }
    for (; p + 4 <= pe; p += 4) {
      u32 e[4], w[4];
      #pragma unroll
      for (int j = 0; j < 4; ++j) e[j] = csr32[p + j];
      #pragma unroll
      for (int j = 0; j < 4; ++j)
        w[j] = (u32)h[(size_t)(e[j] & 0xFFFFu) * DOUT + lane];
      #pragma unroll
      for (int j = 0; j < 4; ++j)
        atomicAdd(&accs[wid][(int)(e[j] >> 16)][lane], __uint_as_float(w[j] << 16));
    }
    for (; p < pe; ++p) {
      u32 e = csr32[p];
      u32 w = (u32)h[(size_t)(e & 0xFFFFu) * DOUT + lane];
      atomicAdd(&accs[wid][(int)(e >> 16)][lane], __uint_as_float(w << 16));
    }
  }
  #pragma unroll
  for (int k = 0; k < KOWN; ++k) {
    int nd = gw * KOWN + k;
    if (nd < n)
      out[(size_t)nd * DOUT + lane] = fmaf(accs[wid][k][lane], dinv[nd], bias[lane]);
  }
}

// ---------- launch ----------

extern "C" void kernel_launch(void* const* d_in, const int* in_sizes, int n_in,
                              void* d_out, int out_size, void* d_ws, size_t ws_size,
                              hipStream_t stream) {
  const float* x  = (const float*)d_in[0];
  const int*   ei = (const int*)d_in[1];
  const float* W1 = (const float*)d_in[2];
  const float* b1 = (const float*)d_in[3];
  const float* W2 = (const float*)d_in[4];
  const float* b2 = (const float*)d_in[5];
  float* out = (float*)d_out;

  const int N = in_sizes[0] / DIN;   // 50000
  const int E = in_sizes[1] / 2;     // 1600000
  const int* src = ei;
  const int* dst = ei + E;
  const int nbuk = (N + BNODES - 1) / BNODES;   // 391 (<= MAXBUK)
  const int M2 = nbuk * 16 * NRANGE;            // (wave,phase) segments incl. phantoms
  const int NB2 = (M2 + 255) / 256;
  const int nwave = (N + KOWN - 1) / KOWN;      // 6250
  const int aggblk = (nwave + 3) / 4;           // 1563 blocks (4 waves each)

  char* ws = (char*)d_ws;
  size_t o = 0;
  auto alloc = [&](size_t bytes) { size_t r = o; o += (bytes + 511) & ~(size_t)511; return r; };
  size_t colsum_o  = alloc((size_t)(nbuk + 1) * 4);
  size_t counts_o  = alloc((size_t)nbuk * NBLK * 4);
  size_t rowptr_o  = alloc((size_t)(M2 + 1) * 4);
  size_t partial_o = alloc((size_t)NB2 * 4);
  size_t dinv_o    = alloc((size_t)N * 4);
  size_t cnt_o     = alloc((size_t)M2 * 4);
  size_t w1t_o     = alloc((size_t)DH * DIN * 2);
  size_t w2t_o     = alloc((size_t)DOUT * DH * 2);
  size_t csr_o     = alloc((size_t)E * 4);        // u32 entries (k<<16|src)
  size_t h1_o      = alloc((size_t)N * DH * 2);   // bf16
  size_t g1_o      = alloc((size_t)N * DH * 2);   // bf16 (GEMM2 input)
  size_t ebuf_o    = alloc((size_t)E * 4);
  size_t h2_o      = h1_o;   // h1 dead after aggregate1w -> reuse (bf16)

  int*   colsum  = (int*)(ws + colsum_o);   // becomes bb after scan_block
  int*   counts  = (int*)(ws + counts_o);
  int*   rowptr  = (int*)(ws + rowptr_o);
  int*   partial = (int*)(ws + partial_o);
  float* dinv    = (float*)(ws + dinv_o);
  int*   cnt     = (int*)(ws + cnt_o);
  u16*   w1t     = (u16*)(ws + w1t_o);
  u16*   w2t     = (u16*)(ws + w2t_o);
  u32*   csr32   = (u32*)(ws + csr_o);
  u16*   h1      = (u16*)(ws + h1_o);
  u16*   g1      = (u16*)(ws + g1_o);
  u16*   h2      = (u16*)(ws + h2_o);
  u32*   ebuf    = (u32*)(ws + ebuf_o);

  w_prep<<<(DH * DIN + DOUT * DH) / 256, 256, 0, stream>>>(W1, W2, w1t, w2t);
  hist_kernel<<<NBLK, 256, 0, stream>>>(dst, counts, E, nbuk);
  col_scan<<<nbuk, 256, 0, stream>>>(counts, colsum, nbuk);
  scan_block<<<1, 256, 0, stream>>>(colsum, colsum, nbuk, nbuk);  // colsum -> bb, bb[nbuk]=E
  scatter_kernel<<<NBLK, 256, 0, stream>>>(src, dst, counts, colsum, ebuf, E, nbuk);
  bucket_node_count<<<nbuk, 256, 0, stream>>>(ebuf, colsum, cnt, dinv, N);
  reduce_chunks<<<NB2, 256, 0, stream>>>(cnt, partial, M2);
  scan_block<<<1, 256, 0, stream>>>(partial, rowptr, NB2, M2);    // rowptr[M2]=E
  scan_chunks<<<NB2, 256, 0, stream>>>(cnt, partial, rowptr, M2);
  bucket_fill<<<nbuk, 256, 0, stream>>>(ebuf, colsum, rowptr, csr32);

  gemm1_mfma<<<(N + 63) / 64, 256, 0, stream>>>(x, w1t, dinv, h1, N);
  aggregate1w<<<aggblk, 256, 0, stream>>>(h1, rowptr, csr32, dinv, b1, g1, N, nwave);
  gemm2_mfma<<<(N + 63) / 64, 256, 0, stream>>>(g1, w2t, dinv, h2, N);
  aggregate2w<<<aggblk, 256, 0, stream>>>(h2, rowptr, csr32, dinv, b2, out, N, nwave);
}

// Round 11
// 251.151 us; speedup vs baseline: 7.7581x; 7.7581x over previous
//
#include <hip/hip_runtime.h>

#define DIN 256
#define DH  128
#define DOUT 64
#define BSH  7          // bucket = 128 nodes
#define BNODES 128
#define MAXBUK 400      // >= ceil(N/128); N=50000 -> 391
#define NBLK 512        // histogram/scatter grid
#define WPREP_BLOCKS ((DH * DIN + DOUT * DH) / 256)   // 160

typedef unsigned int  u32;
typedef unsigned short u16;
typedef __attribute__((ext_vector_type(8))) short bf16x8;
typedef __attribute__((ext_vector_type(4))) float f32x4;

__device__ inline u16 f2bf(float f) {            // fp32 -> bf16 round-nearest-even
  u32 u = __float_as_uint(f);
  u32 r = u + 0x7FFF + ((u >> 16) & 1);
  return (u16)(r >> 16);
}
__device__ inline float bf2f_lo(u32 packed) { return __uint_as_float(packed << 16); }
__device__ inline float bf2f_hi(u32 packed) { return __uint_as_float(packed & 0xFFFF0000u); }

// ---------- k1: fused histogram + weight prep + counter zeroing ----------
// blocks [0,NBLK): per-block bucket histogram of dst -> counts[buk][blk]
// blocks [NBLK, NBLK+WPREP_BLOCKS): W1/W2 -> bf16 transposed
// block NBLK, thread 0..1: zero the two reservation counters

__global__ __launch_bounds__(256) void hist_prep(const int* __restrict__ dst,
    int* __restrict__ counts, const float* __restrict__ W1, const float* __restrict__ W2,
    u16* __restrict__ w1t, u16* __restrict__ w2t, int* __restrict__ gctr,
    int E, int nbuk) {
  int tid = threadIdx.x, b = blockIdx.x;
  if (b < NBLK) {
    __shared__ int h[MAXBUK];
    for (int i = tid; i < nbuk; i += 256) h[i] = 0;
    __syncthreads();
    int ech = (E + NBLK - 1) / NBLK;
    int e0 = b * ech, e1 = min(E, e0 + ech);
    for (int e = e0 + tid; e < e1; e += 256)
      atomicAdd(&h[dst[e] >> BSH], 1);
    __syncthreads();
    for (int i = tid; i < nbuk; i += 256) counts[(size_t)i * NBLK + b] = h[i];
  } else {
    if (b == NBLK && tid < 2) gctr[tid] = 0;
    int t = (b - NBLK) * 256 + tid;
    if (t < DH * DIN) {
      int n = t >> 8, k = t & 255;
      w1t[t] = f2bf(W1[k * DH + n]);            // w1t[n*256+k]
    } else {
      int t2 = t - DH * DIN;
      int n = t2 >> 7, k = t2 & 127;
      w2t[t2] = f2bf(W2[k * DOUT + n]);         // w2t[n*128+k]
    }
  }
}

// ---------- k2: per-bucket scan of counts row + atomic range reservation ----------
// Bucket placement in ebuf is arrival-ordered (NOT index-ordered) — correctness
// only needs each bucket's region contiguous + base recorded in bb[].
// Pre-adds base into counts cells so scatter uses them as absolute cursors.

__global__ __launch_bounds__(256) void col_scan(int* __restrict__ counts,
    int* __restrict__ bb, int* __restrict__ colsum, int* __restrict__ gctr, int nbuk) {
  __shared__ int sm[256];
  __shared__ int shbase;
  int buk = blockIdx.x, t = threadIdx.x;
  int* row = counts + (size_t)buk * NBLK;
  int v0 = row[t], v1 = row[256 + t];
  // round 1 scan
  sm[t] = v0;
  __syncthreads();
  for (int d = 1; d < 256; d <<= 1) {
    int a = (t >= d) ? sm[t - d] : 0;
    __syncthreads();
    sm[t] += a;
    __syncthreads();
  }
  int excl0 = sm[t] - v0;
  int carry = sm[255];   // all threads read after barrier below
  __syncthreads();
  // round 2 scan
  sm[t] = v1;
  __syncthreads();
  for (int d = 1; d < 256; d <<= 1) {
    int a = (t >= d) ? sm[t - d] : 0;
    __syncthreads();
    sm[t] += a;
    __syncthreads();
  }
  int excl1 = sm[t] - v1 + carry;
  int total = sm[255] + carry;
  __syncthreads();
  if (t == 0) shbase = atomicAdd(&gctr[0], total);
  __syncthreads();
  int base = shbase;
  row[t] = base + excl0;
  row[256 + t] = base + excl1;
  if (t == 0) { bb[buk] = base; colsum[buk] = total; }
}

// ---------- k3: scatter packed (nodeLow<<16|src) into bucket regions ----------

__global__ __launch_bounds__(256) void scatter_kernel(const int* __restrict__ src,
    const int* __restrict__ dst, const int* __restrict__ counts,
    u32* __restrict__ ebuf, int E, int nbuk) {
  __shared__ int cur[MAXBUK];
  int tid = threadIdx.x, b = blockIdx.x;
  for (int i = tid; i < nbuk; i += 256)
    cur[i] = counts[(size_t)i * NBLK + b];          // absolute cursor (base pre-added)
  __syncthreads();
  int ech = (E + NBLK - 1) / NBLK;
  int e0 = b * ech, e1 = min(E, e0 + ech);
  for (int e = e0 + tid; e < e1; e += 256) {
    int d = dst[e];
    int r = atomicAdd(&cur[d >> BSH], 1);
    ebuf[r] = (u32)src[e] | ((u32)(d & (BNODES - 1)) << 16);   // N < 65536
  }
}

// ---------- k4: fused bucket build: node counts -> dinv/cnt/rowptr -> csr fill ----------
// One block per bucket. csr region reserved via atomicAdd (arrival order; fine).

__global__ __launch_bounds__(256) void bucket_build(const u32* __restrict__ ebuf,
    const int* __restrict__ bb, const int* __restrict__ colsum,
    int* __restrict__ gctr, int* __restrict__ rowptr, int* __restrict__ cnt,
    float* __restrict__ dinv, u16* __restrict__ csr, int N) {
  __shared__ int cn[BNODES];
  __shared__ int sm[BNODES];
  __shared__ int cur[BNODES];
  __shared__ int shbase;
  int b = blockIdx.x, tid = threadIdx.x;
  if (tid < BNODES) cn[tid] = 0;
  __syncthreads();
  int e0 = bb[b], e1 = e0 + colsum[b];
  for (int e = e0 + tid; e < e1; e += 256)
    atomicAdd(&cn[ebuf[e] >> 16], 1);
  __syncthreads();
  if (tid == 0) shbase = atomicAdd(&gctr[1], e1 - e0);
  // in-block exclusive scan of cn[128]
  if (tid < BNODES) sm[tid] = cn[tid];
  __syncthreads();
  for (int d = 1; d < BNODES; d <<= 1) {
    int a = (tid < BNODES && tid >= d) ? sm[tid - d] : 0;
    __syncthreads();
    if (tid < BNODES) sm[tid] += a;
    __syncthreads();
  }
  int base = shbase;
  if (tid < BNODES) {
    int excl = sm[tid] - cn[tid];
    cur[tid] = base + excl;
    int node = b * BNODES + tid;
    if (node < N) {
      rowptr[node] = base + excl;
      cnt[node] = cn[tid];
      dinv[node] = rsqrtf((float)(cn[tid] + 1));   // +1 self-loop
    }
  }
  __syncthreads();
  for (int e = e0 + tid; e < e1; e += 256) {
    u32 p = ebuf[e];
    int pos = atomicAdd(&cur[p >> 16], 1);
    csr[pos] = (u16)(p & 0xFFFFu);
  }
}

// ---------- GEMM1: bf16 MFMA, BM=64 BN=128 BK=64, epilogue dinv*bf16 ----------

__global__ __launch_bounds__(256) void gemm1_mfma(const float* __restrict__ x,
    const u16* __restrict__ w1t, const float* __restrict__ dinv,
    u16* __restrict__ h1, int M) {
  __shared__ u16 As[64][72];
  __shared__ u16 Bs[128][72];
  const int tid = threadIdx.x;
  const int lane = tid & 63, w = tid >> 6;
  const int row16 = lane & 15, quad = lane >> 4;
  const int rowBase = blockIdx.x * 64;
  f32x4 acc[8];
  #pragma unroll
  for (int nt = 0; nt < 8; ++nt) acc[nt] = (f32x4)(0.f);

  for (int kt = 0; kt < DIN; kt += 64) {
    {
      int r = tid >> 2, kq = tid & 3;
      int grow = rowBase + r;
      #pragma unroll
      for (int i = 0; i < 4; ++i) {
        float4 v = make_float4(0.f, 0.f, 0.f, 0.f);
        if (grow < M) v = *(const float4*)&x[(size_t)grow * DIN + kt + kq * 16 + i * 4];
        u32 lo = (u32)f2bf(v.x) | ((u32)f2bf(v.y) << 16);
        u32 hi = (u32)f2bf(v.z) | ((u32)f2bf(v.w) << 16);
        *(uint2*)&As[r][kq * 16 + i * 4] = make_uint2(lo, hi);
      }
    }
    {
      int n = tid >> 1, half = tid & 1;
      const uint4* s = (const uint4*)&w1t[n * DIN + kt + half * 32];
      uint4* d = (uint4*)&Bs[n][half * 32];
      d[0] = s[0]; d[1] = s[1]; d[2] = s[2]; d[3] = s[3];
    }
    __syncthreads();
    #pragma unroll
    for (int ks = 0; ks < 64; ks += 32) {
      bf16x8 a = *(bf16x8*)&As[w * 16 + row16][ks + quad * 8];
      #pragma unroll
      for (int nt = 0; nt < 8; ++nt) {
        bf16x8 b = *(bf16x8*)&Bs[nt * 16 + row16][ks + quad * 8];
        acc[nt] = __builtin_amdgcn_mfma_f32_16x16x32_bf16(a, b, acc[nt], 0, 0, 0);
      }
    }
    __syncthreads();
  }
  #pragma unroll
  for (int reg = 0; reg < 4; ++reg) {
    int row = rowBase + w * 16 + quad * 4 + reg;
    if (row < M) {
      float s = dinv[row];
      #pragma unroll
      for (int nt = 0; nt < 8; ++nt)
        h1[(size_t)row * DH + nt * 16 + row16] = f2bf(acc[nt][reg] * s);
    }
  }
}

// ---------- GEMM2: bf16 MFMA, BM=64 BN=64, K=128 staged once ----------

__global__ __launch_bounds__(256) void gemm2_mfma(const u16* __restrict__ g1,
    const u16* __restrict__ w2t, const float* __restrict__ dinv,
    u16* __restrict__ h2, int M) {
  __shared__ u16 As[64][136];
  __shared__ u16 Bs[64][136];
  const int tid = threadIdx.x;
  const int lane = tid & 63, w = tid >> 6;
  const int row16 = lane & 15, quad = lane >> 4;
  const int rowBase = blockIdx.x * 64;
  f32x4 acc[4];
  #pragma unroll
  for (int nt = 0; nt < 4; ++nt) acc[nt] = (f32x4)(0.f);

  #pragma unroll
  for (int i = 0; i < 4; ++i) {
    int flat = i * 256 + tid;
    int r = flat >> 4, c = flat & 15;
    int grow = rowBase + r;
    uint4 v = make_uint4(0, 0, 0, 0);
    if (grow < M) v = *(const uint4*)&g1[(size_t)grow * DH + c * 8];
    *(uint4*)&As[r][c * 8] = v;
  }
  #pragma unroll
  for (int i = 0; i < 4; ++i) {
    int flat = i * 256 + tid;
    int r = flat >> 4, c = flat & 15;
    *(uint4*)&Bs[r][c * 8] = *(const uint4*)&w2t[r * DH + c * 8];
  }
  __syncthreads();
  #pragma unroll
  for (int ks = 0; ks < 128; ks += 32) {
    bf16x8 a = *(bf16x8*)&As[w * 16 + row16][ks + quad * 8];
    #pragma unroll
    for (int nt = 0; nt < 4; ++nt) {
      bf16x8 b = *(bf16x8*)&Bs[nt * 16 + row16][ks + quad * 8];
      acc[nt] = __builtin_amdgcn_mfma_f32_16x16x32_bf16(a, b, acc[nt], 0, 0, 0);
    }
  }
  #pragma unroll
  for (int reg = 0; reg < 4; ++reg) {
    int row = rowBase + w * 16 + quad * 4 + reg;
    if (row < M) {
      float s = dinv[row];
      #pragma unroll
      for (int nt = 0; nt < 4; ++nt)
        h2[(size_t)row * DOUT + nt * 16 + row16] = f2bf(acc[nt][reg] * s);
    }
  }
}

// ---------- pull aggregation (R8-proven): one wave per node, 16-deep, u16 csr ----------

__global__ __launch_bounds__(256) void aggregate1(const u16* __restrict__ h,
    const int* __restrict__ rowptr, const int* __restrict__ cnt,
    const u16* __restrict__ csr, const float* __restrict__ dinv,
    const float* __restrict__ bias, u16* __restrict__ out, int n) {
  int lane = threadIdx.x & 63;
  int node = blockIdx.x * 4 + (threadIdx.x >> 6);
  if (node >= n) return;
  node = __builtin_amdgcn_readfirstlane(node);
  float di = dinv[node];
  int c0 = lane * 2;
  u32 w0 = *(const u32*)&h[(size_t)node * DH + c0];   // self-loop (pre-scaled)
  float ax = bf2f_lo(w0), ay = bf2f_hi(w0);
  int p = rowptr[node], pe = p + cnt[node];
  for (; p + 16 <= pe; p += 16) {
    int s[16];
    #pragma unroll
    for (int j = 0; j < 16; ++j) s[j] = csr[p + j];
    #pragma unroll
    for (int j = 0; j < 16; ++j) {
      u32 w = *(const u32*)&h[(size_t)s[j] * DH + c0];
      ax += bf2f_lo(w); ay += bf2f_hi(w);
    }
  }
  for (; p + 4 <= pe; p += 4) {
    int s[4];
    #pragma unroll
    for (int j = 0; j < 4; ++j) s[j] = csr[p + j];
    #pragma unroll
    for (int j = 0; j < 4; ++j) {
      u32 w = *(const u32*)&h[(size_t)s[j] * DH + c0];
      ax += bf2f_lo(w); ay += bf2f_hi(w);
    }
  }
  for (; p < pe; ++p) {
    u32 w = *(const u32*)&h[(size_t)csr[p] * DH + c0];
    ax += bf2f_lo(w); ay += bf2f_hi(w);
  }
  ax = fmaxf(fmaf(ax, di, bias[c0]), 0.f);
  ay = fmaxf(fmaf(ay, di, bias[c0 + 1]), 0.f);
  *(u32*)&out[(size_t)node * DH + c0] = (u32)f2bf(ax) | ((u32)f2bf(ay) << 16);
}

__global__ __launch_bounds__(256) void aggregate2(const u16* __restrict__ h,
    const int* __restrict__ rowptr, const int* __restrict__ cnt,
    const u16* __restrict__ csr, const float* __restrict__ dinv,
    const float* __restrict__ bias, float* __restrict__ out, int n) {
  int lane = threadIdx.x & 63;
  int node = blockIdx.x * 4 + (threadIdx.x >> 6);
  if (node >= n) return;
  node = __builtin_amdgcn_readfirstlane(node);
  float di = dinv[node];
  float a = __uint_as_float((u32)h[(size_t)node * DOUT + lane] << 16);
  int p = rowptr[node], pe = p + cnt[node];
  for (; p + 16 <= pe; p += 16) {
    int s[16];
    #pragma unroll
    for (int j = 0; j < 16; ++j) s[j] = csr[p + j];
    #pragma unroll
    for (int j = 0; j < 16; ++j)
      a += __uint_as_float((u32)h[(size_t)s[j] * DOUT + lane] << 16);
  }
  for (; p + 4 <= pe; p += 4) {
    int s[4];
    #pragma unroll
    for (int j = 0; j < 4; ++j) s[j] = csr[p + j];
    #pragma unroll
    for (int j = 0; j < 4; ++j)
      a += __uint_as_float((u32)h[(size_t)s[j] * DOUT + lane] << 16);
  }
  for (; p < pe; ++p)
    a += __uint_as_float((u32)h[(size_t)csr[p] * DOUT + lane] << 16);
  out[(size_t)node * DOUT + lane] = fmaf(a, di, bias[lane]);
}

// ---------- launch (8 dispatches, no memset) ----------

extern "C" void kernel_launch(void* const* d_in, const int* in_sizes, int n_in,
                              void* d_out, int out_size, void* d_ws, size_t ws_size,
                              hipStream_t stream) {
  const float* x  = (const float*)d_in[0];
  const int*   ei = (const int*)d_in[1];
  const float* W1 = (const float*)d_in[2];
  const float* b1 = (const float*)d_in[3];
  const float* W2 = (const float*)d_in[4];
  const float* b2 = (const float*)d_in[5];
  float* out = (float*)d_out;

  const int N = in_sizes[0] / DIN;   // 50000
  const int E = in_sizes[1] / 2;     // 1600000
  const int* src = ei;
  const int* dst = ei + E;
  const int nbuk = (N + BNODES - 1) / BNODES;   // 391 (<= MAXBUK)

  char* ws = (char*)d_ws;
  size_t o = 0;
  auto alloc = [&](size_t bytes) { size_t r = o; o += (bytes + 511) & ~(size_t)511; return r; };
  size_t gctr_o    = alloc(2 * 4);
  size_t bb_o      = alloc((size_t)nbuk * 4);
  size_t colsum_o  = alloc((size_t)nbuk * 4);
  size_t counts_o  = alloc((size_t)nbuk * NBLK * 4);
  size_t rowptr_o  = alloc((size_t)N * 4);
  size_t cnt_o     = alloc((size_t)N * 4);
  size_t dinv_o    = alloc((size_t)N * 4);
  size_t w1t_o     = alloc((size_t)DH * DIN * 2);
  size_t w2t_o     = alloc((size_t)DOUT * DH * 2);
  size_t csr_o     = alloc((size_t)E * 2);        // u16
  size_t h1_o      = alloc((size_t)N * DH * 2);   // bf16
  size_t g1_o      = alloc((size_t)N * DH * 2);   // bf16 (GEMM2 input)
  size_t ebuf_o    = alloc((size_t)E * 4);
  size_t h2_o      = h1_o;   // h1 dead after aggregate1 -> reuse (bf16)

  int*   gctr    = (int*)(ws + gctr_o);
  int*   bb      = (int*)(ws + bb_o);
  int*   colsum  = (int*)(ws + colsum_o);
  int*   counts  = (int*)(ws + counts_o);
  int*   rowptr  = (int*)(ws + rowptr_o);
  int*   cnt     = (int*)(ws + cnt_o);
  float* dinv    = (float*)(ws + dinv_o);
  u16*   w1t     = (u16*)(ws + w1t_o);
  u16*   w2t     = (u16*)(ws + w2t_o);
  u16*   csr     = (u16*)(ws + csr_o);
  u16*   h1      = (u16*)(ws + h1_o);
  u16*   g1      = (u16*)(ws + g1_o);
  u16*   h2      = (u16*)(ws + h2_o);
  u32*   ebuf    = (u32*)(ws + ebuf_o);

  hist_prep<<<NBLK + WPREP_BLOCKS, 256, 0, stream>>>(dst, counts, W1, W2, w1t, w2t,
                                                     gctr, E, nbuk);
  col_scan<<<nbuk, 256, 0, stream>>>(counts, bb, colsum, gctr, nbuk);
  scatter_kernel<<<NBLK, 256, 0, stream>>>(src, dst, counts, ebuf, E, nbuk);
  bucket_build<<<nbuk, 256, 0, stream>>>(ebuf, bb, colsum, gctr, rowptr, cnt,
                                         dinv, csr, N);

  gemm1_mfma<<<(N + 63) / 64, 256, 0, stream>>>(x, w1t, dinv, h1, N);
  aggregate1<<<(N + 3) / 4, 256, 0, stream>>>(h1, rowptr, cnt, csr, dinv, b1, g1, N);
  gemm2_mfma<<<(N + 63) / 64, 256, 0, stream>>>(g1, w2t, dinv, h2, N);
  aggregate2<<<(N + 3) / 4, 256, 0, stream>>>(h2, rowptr, cnt, csr, dinv, b2, out, N);
}